// Round 16
// baseline (37.600 us; speedup 1.0000x reference)
//
#include <hip/hip_runtime.h>

#define HH 128
#define WW 128
#define KK 64
#define SS 16
#define S3 (SS * SS * SS)
#define VOLRADIUS 256.0f
#define CULL_EPS 1e-3f

// ---- DPP inclusive scans (gfx9 pattern: row_shr 1/2/4/8 + row_bcast 15/31) ----
template <int CTRL, int RM>
__device__ __forceinline__ float dpp_addf(float x) {
    int y = __builtin_amdgcn_update_dpp(0, __float_as_int(x), CTRL, RM, 0xF, false);
    return x + __int_as_float(y);
}
__device__ __forceinline__ float wave_incl_scan(float x) {
    x = dpp_addf<0x111, 0xF>(x);
    x = dpp_addf<0x112, 0xF>(x);
    x = dpp_addf<0x114, 0xF>(x);
    x = dpp_addf<0x118, 0xF>(x);
    x = dpp_addf<0x142, 0xA>(x);   // row_bcast:15 -> rows 1,3
    x = dpp_addf<0x143, 0xC>(x);   // row_bcast:31 -> rows 2,3
    return x;
}
__device__ __forceinline__ int wave_incl_scan_addi(int x) {
    int y;
    y = __builtin_amdgcn_update_dpp(0, x, 0x111, 0xF, 0xF, false); x += y;
    y = __builtin_amdgcn_update_dpp(0, x, 0x112, 0xF, 0xF, false); x += y;
    y = __builtin_amdgcn_update_dpp(0, x, 0x114, 0xF, 0xF, false); x += y;
    y = __builtin_amdgcn_update_dpp(0, x, 0x118, 0xF, 0xF, false); x += y;
    y = __builtin_amdgcn_update_dpp(0, x, 0x142, 0xA, 0xF, false); x += y;
    y = __builtin_amdgcn_update_dpp(0, x, 0x143, 0xC, 0xF, false); x += y;
    return x;
}

#define LERP4(a, b, f) make_float4(a.x*(1.f-(f)) + b.x*(f), a.y*(1.f-(f)) + b.y*(f), \
                                   a.z*(1.f-(f)) + b.z*(f), a.w*(1.f-(f)) + b.w*(f))

// template [K,4,S,S,S] -> ws [K,S,S,S,4] so each trilinear corner is one float4
__global__ __launch_bounds__(256) void transpose_tpl(const float* __restrict__ tpl,
                                                     float4* __restrict__ tw) {
    int i = blockIdx.x * blockDim.x + threadIdx.x;      // 0 .. K*S3
    if (i >= KK * S3) return;
    int k = i >> 12, v = i & (S3 - 1);
    const float* src = tpl + ((size_t)k * 4 * S3) + v;
    tw[i] = make_float4(src[0], src[S3], src[2 * S3], src[3 * S3]);
}

template <bool TR>
__global__ __launch_bounds__(256, 8) void raymarch_kernel(
    const float* __restrict__ viewpos,   // [3]
    const float* __restrict__ raydir,    // [H,W,3]
    const float* __restrict__ tpl,       // [K,4,S,S,S]
    const float* __restrict__ primpos,   // [K,3]
    const float* __restrict__ primrot,   // [K,3,3]
    const float* __restrict__ primscale, // [K,3]
    const float* __restrict__ dtp,       // [1]
    const float4* __restrict__ tw,       // [K,S3] rgba (if TR)
    float* __restrict__ out)
{
    const int lane = (int)(threadIdx.x & 63);
    const int wvid = (int)(threadIdx.x >> 6);      // wave within block (0..3)
    const int wid = __builtin_amdgcn_readfirstlane(
        (int)((blockIdx.x * blockDim.x + threadIdx.x) >> 6));
    if (wid >= HH * WW) return;
    // bijective swizzle: spread heavy central rows across the dispatch order
    const int pix = ((wid & 63) << 8) | (wid >> 6);

    __shared__ float4 accs[4][64];                 // per-(wave,step) RGBA partials
    accs[wvid][lane] = make_float4(0.f, 0.f, 0.f, 0.f);   // own-wave region

    const float vx = viewpos[0] / VOLRADIUS;
    const float vy = viewpos[1] / VOLRADIUS;
    const float vz = viewpos[2] / VOLRADIUS;
    const float dtn = dtp[0] / VOLRADIUS;

    const float Rx = raydir[pix*3+0], Ry = raydir[pix*3+1], Rz = raydir[pix*3+2];

    // slab vs [-1,1]^3, exactly as reference
    float t1x = (-1.f-vx)/Rx, t2x = (1.f-vx)/Rx;
    float t1y = (-1.f-vy)/Ry, t2y = (1.f-vy)/Ry;
    float t1z = (-1.f-vz)/Rz, t2z = (1.f-vz)/Rz;
    float tmin = fmaxf(fminf(t1x,t2x), fmaxf(fminf(t1y,t2y), fminf(t1z,t2z)));
    float tmax = fminf(fmaxf(t1x,t2x), fminf(fmaxf(t1y,t2y), fmaxf(t1z,t2z)));
    bool inter = tmin < tmax;
    float tmin_ = inter ? tmin : 0.f;
    float tmax_ = inter ? tmax : 0.f;
    float t0 = fmaxf(tmin_, 0.f);

    // this lane's primitive params, held live for cross-lane fetch later
    const float px = primpos[lane*3+0], py = primpos[lane*3+1], pz = primpos[lane*3+2];
    const float r00 = primrot[lane*9+0], r01 = primrot[lane*9+1], r02 = primrot[lane*9+2];
    const float r10 = primrot[lane*9+3], r11 = primrot[lane*9+4], r12 = primrot[lane*9+5];
    const float r20 = primrot[lane*9+6], r21 = primrot[lane*9+7], r22 = primrot[lane*9+8];
    const float sx = primscale[lane*3+0], sy = primscale[lane*3+1], sz = primscale[lane*3+2];

    // ---- cull: conservative ray-vs-OBB -> conservative STEP RANGE per prim ----
    int ilo = 0, icnt = 0;
    {
        float bb[3], dd[3];
        bb[0] = ((vx-px)*r00 + (vy-py)*r10 + (vz-pz)*r20) * sx;
        bb[1] = ((vx-px)*r01 + (vy-py)*r11 + (vz-pz)*r21) * sy;
        bb[2] = ((vx-px)*r02 + (vy-py)*r12 + (vz-pz)*r22) * sz;
        dd[0] = (Rx*r00 + Ry*r10 + Rz*r20) * sx;
        dd[1] = (Rx*r01 + Ry*r11 + Rz*r21) * sy;
        dd[2] = (Rx*r02 + Ry*r12 + Rz*r22) * sz;
        float tend = fminf(tmax_, t0 + 63.f*dtn);
        float te = t0, tx = tend;
#pragma unroll
        for (int j = 0; j < 3; ++j) {
            float ta, tb2;
            if (fabsf(dd[j]) > 1e-12f) {
                float inv = 1.f / dd[j];
                ta  = (-1.f - CULL_EPS - bb[j]) * inv;
                tb2 = ( 1.f + CULL_EPS - bb[j]) * inv;
            } else {
                bool ok = fabsf(bb[j]) <= 1.f + CULL_EPS;
                ta  = ok ? -3e38f :  3e38f;
                tb2 = ok ?  3e38f : -3e38f;
            }
            te = fmaxf(te, fminf(ta, tb2));
            tx = fminf(tx, fmaxf(ta, tb2));
        }
        if (te <= tx) {
            // tightened conservative bounds: true-inside steps sit >= ~5e-3 step
            // units inside [te,tx] (CULL_EPS margin / |d| >= 1.25e-4 t-units);
            // 0.01 margin keeps a strict superset while dropping ~2 cand/prim.
            float flo = (te - t0) / dtn - 0.01f;
            float fhi = (tx - t0) / dtn + 0.01f;
            ilo = max(0, (int)ceilf(flo));
            int ihi = min(63, (int)floorf(fhi));
            icnt = max(0, ihi - ilo + 1);
        }
    }

    float sv0, sv1, sv2, sv3;

    if (TR) {
        // ---- closed-form candidate enumeration, pure-register owner search ----
        const int Ainc  = wave_incl_scan_addi(icnt);
        const int start = Ainc - icnt;                 // exclusive prefix (sorted by lane)
        const int Ctot  = __builtin_amdgcn_readlane(Ainc, 63);
        const int nw    = (Ctot + 63) >> 6;

        for (int b = 0; b < nw; ++b) {
            const int s  = (b << 6) + lane;            // candidate slot
            const bool act = s < Ctot;

            // owner = largest lane p with start[p] <= s  (start[0]==0 <= s)
            int p = 0;
#pragma unroll
            for (int st = 32; st > 0; st >>= 1) {
                int cand = p | st;                     // <= 63 by construction
                int sp = __shfl(start, cand, 64);
                if (sp <= s) p = cand;
            }
            const int pst = __shfl(start, p, 64);
            const int il  = __shfl(ilo,   p, 64);
            const int ic  = __shfl(icnt,  p, 64);
            const int i   = il + (s - pst);            // step index, <= ihi <= 63 when in range
            const bool inrange = act && (s - pst) < ic;

            // fetch prim p's params cross-lane (bit-exact register moves)
            float qpx = __shfl(px, p, 64), qpy = __shfl(py, p, 64), qpz = __shfl(pz, p, 64);
            float q00 = __shfl(r00, p, 64), q01 = __shfl(r01, p, 64), q02 = __shfl(r02, p, 64);
            float q10 = __shfl(r10, p, 64), q11 = __shfl(r11, p, 64), q12 = __shfl(r12, p, 64);
            float q20 = __shfl(r20, p, 64), q21 = __shfl(r21, p, 64), q22 = __shfl(r22, p, 64);
            float qsx = __shfl(sx, p, 64), qsy = __shfl(sy, p, 64), qsz = __shfl(sz, p, 64);

            // exact per-candidate math (identical expressions to reference)
            float ti = t0 + (float)i * dtn;
            float posx = vx + Rx*ti, posy = vy + Ry*ti, posz = vz + Rz*ti;
            float xmx = posx-qpx, xmy = posy-qpy, xmz = posz-qpz;
            float y0 = (xmx*q00 + xmy*q10 + xmz*q20) * qsx;
            float y1 = (xmx*q01 + xmy*q11 + xmz*q21) * qsy;
            float y2 = (xmx*q02 + xmy*q12 + xmz*q22) * qsz;
            bool samp = inrange && (ti < tmax_) &&
                        fabsf(y0) < 1.f && fabsf(y1) < 1.f && fabsf(y2) < 1.f;
            if (samp) {
                float gx = (y0+1.f)*(0.5f*(SS-1));
                float gy = (y1+1.f)*(0.5f*(SS-1));
                float gz = (y2+1.f)*(0.5f*(SS-1));
                int x0  = min(max((int)floorf(gx), 0), SS-2);
                int y0i = min(max((int)floorf(gy), 0), SS-2);
                int z0  = min(max((int)floorf(gz), 0), SS-2);
                float fx = gx-(float)x0, fy = gy-(float)y0i, fz = gz-(float)z0;
                int idx = z0*(SS*SS) + y0i*SS + x0;
                const float4* tb = tw + ((size_t)p << 12) + idx;
                float4 c000 = tb[0],          c001 = tb[1];
                float4 c010 = tb[SS],         c011 = tb[SS+1];
                float4 c100 = tb[SS*SS],      c101 = tb[SS*SS+1];
                float4 c110 = tb[SS*SS+SS],   c111 = tb[SS*SS+SS+1];
                float4 c00 = LERP4(c000, c001, fx);
                float4 c01 = LERP4(c010, c011, fx);
                float4 c10 = LERP4(c100, c101, fx);
                float4 c11 = LERP4(c110, c111, fx);
                float4 e0  = LERP4(c00, c01, fy);
                float4 e1  = LERP4(c10, c11, fy);
                float* ap = (float*)&accs[wvid][i];
                atomicAdd(ap + 0, e0.x*(1.f-fz) + e1.x*fz);
                atomicAdd(ap + 1, e0.y*(1.f-fz) + e1.y*fz);
                atomicAdd(ap + 2, e0.z*(1.f-fz) + e1.z*fz);
                atomicAdd(ap + 3, e0.w*(1.f-fz) + e1.w*fz);
            }
        }
        // own-wave DS ops complete in order; no cross-wave sharing -> no barrier
        float4 a = accs[wvid][lane];
        sv0 = a.x; sv1 = a.y; sv2 = a.z; sv3 = a.w;
    } else {
        // fallback: r6-style uniform prim loop on original layout
        unsigned long long mask = __ballot(icnt > 0);
        const float t = t0 + (float)lane * dtn;
        const bool tvalid = t < tmax_;
        const float posx = vx + Rx*t, posy = vy + Ry*t, posz = vz + Rz*t;
        sv0 = sv1 = sv2 = sv3 = 0.f;
        while (mask) {
            const int ku = __builtin_amdgcn_readfirstlane(__ffsll(mask) - 1);
            mask &= mask - 1;
            const float qpx = primpos[ku*3+0], qpy = primpos[ku*3+1], qpz = primpos[ku*3+2];
            const float q00 = primrot[ku*9+0], q01 = primrot[ku*9+1], q02 = primrot[ku*9+2];
            const float q10 = primrot[ku*9+3], q11 = primrot[ku*9+4], q12 = primrot[ku*9+5];
            const float q20 = primrot[ku*9+6], q21 = primrot[ku*9+7], q22 = primrot[ku*9+8];
            const float qsx = primscale[ku*3+0], qsy = primscale[ku*3+1], qsz = primscale[ku*3+2];
            float xmx = posx-qpx, xmy = posy-qpy, xmz = posz-qpz;
            float y0 = (xmx*q00 + xmy*q10 + xmz*q20) * qsx;
            float y1 = (xmx*q01 + xmy*q11 + xmz*q21) * qsy;
            float y2 = (xmx*q02 + xmy*q12 + xmz*q22) * qsz;
            bool samp = tvalid && fabsf(y0) < 1.f && fabsf(y1) < 1.f && fabsf(y2) < 1.f;
            if (samp) {
                float gx = (y0+1.f)*(0.5f*(SS-1));
                float gy = (y1+1.f)*(0.5f*(SS-1));
                float gz = (y2+1.f)*(0.5f*(SS-1));
                int x0  = min(max((int)floorf(gx), 0), SS-2);
                int y0i = min(max((int)floorf(gy), 0), SS-2);
                int z0  = min(max((int)floorf(gz), 0), SS-2);
                float fx = gx-(float)x0, fy = gy-(float)y0i, fz = gz-(float)z0;
                int idx = z0*(SS*SS) + y0i*SS + x0;
                const float* tp = tpl + (size_t)ku * (4 * S3);
                float sv[4];
#pragma unroll
                for (int c = 0; c < 4; ++c) {
                    const float* tc = tp + c * S3;
                    float c000 = tc[idx],              c001 = tc[idx+1];
                    float c010 = tc[idx+SS],           c011 = tc[idx+SS+1];
                    float c100 = tc[idx+SS*SS],        c101 = tc[idx+SS*SS+1];
                    float c110 = tc[idx+SS*SS+SS],     c111 = tc[idx+SS*SS+SS+1];
                    float c00 = c000*(1.f-fx) + c001*fx;
                    float c01 = c010*(1.f-fx) + c011*fx;
                    float c10 = c100*(1.f-fx) + c101*fx;
                    float c11 = c110*(1.f-fx) + c111*fx;
                    sv[c] = (c00*(1.f-fy) + c01*fy)*(1.f-fz)
                          + (c10*(1.f-fy) + c11*fy)*fz;
                }
                sv0 += sv[0]; sv1 += sv[1]; sv2 += sv[2]; sv3 += sv[3];
            }
        }
    }

    // ---- compositing in closed form: alpha >= 0 => accA = min(prefix,1) ----
    const float tl = t0 + (float)lane * dtn;
    const bool tvalid = tl < tmax_;
    float alpha = tvalid ? sv3 * dtn : 0.f;
    float A = wave_incl_scan(alpha);               // inclusive prefix of alpha
    float Aex = __shfl_up(A, 1, 64);
    if (lane == 0) Aex = 0.f;
    float contrib = fminf(Aex + alpha, 1.f) - fminf(Aex, 1.f);
    float cr = wave_incl_scan(sv0 * contrib);      // lane63 = total
    float cg = wave_incl_scan(sv1 * contrib);
    float cb = wave_incl_scan(sv2 * contrib);
    float At = fminf(A, 1.f);

    if (lane == 63) {
        out[0*HH*WW + pix] = cr;
        out[1*HH*WW + pix] = cg;
        out[2*HH*WW + pix] = cb;
        out[3*HH*WW + pix] = At;
        const int b1 = 4*HH*WW;
        out[b1 + pix*3+0] = vx + Rx*tmin_;
        out[b1 + pix*3+1] = vy + Ry*tmin_;
        out[b1 + pix*3+2] = vz + Rz*tmin_;
        const int b2 = b1 + HH*WW*3;
        out[b2 + pix*3+0] = vx + Rx*tmax_;
        out[b2 + pix*3+1] = vy + Ry*tmax_;
        out[b2 + pix*3+2] = vz + Rz*tmax_;
    }
}

extern "C" void kernel_launch(void* const* d_in, const int* in_sizes, int n_in,
                              void* d_out, int out_size, void* d_ws, size_t ws_size,
                              hipStream_t stream) {
    const float* viewpos   = (const float*)d_in[0];
    // d_in[1] = viewrot, unused by the reference
    const float* raydir    = (const float*)d_in[2];
    const float* tpl       = (const float*)d_in[3];
    const float* primpos   = (const float*)d_in[4];
    const float* primrot   = (const float*)d_in[5];
    const float* primscale = (const float*)d_in[6];
    const float* dtp       = (const float*)d_in[7];
    float* out = (float*)d_out;

    const size_t twbytes = (size_t)KK * S3 * 4 * sizeof(float);  // 4 MiB
    dim3 block(256), grid(HH * WW * 64 / 256);                    // 4096 blocks

    if (ws_size >= twbytes) {
        transpose_tpl<<<dim3((KK * S3 + 255) / 256), block, 0, stream>>>(tpl, (float4*)d_ws);
        raymarch_kernel<true><<<grid, block, 0, stream>>>(
            viewpos, raydir, tpl, primpos, primrot, primscale, dtp,
            (const float4*)d_ws, out);
    } else {
        raymarch_kernel<false><<<grid, block, 0, stream>>>(
            viewpos, raydir, tpl, primpos, primrot, primscale, dtp,
            (const float4*)d_ws, out);
    }
}

// Round 17
// 30.056 us; speedup vs baseline: 1.2510x; 1.2510x over previous
//
#include <hip/hip_runtime.h>

#define HH 128
#define WW 128
#define KK 64
#define SS 16
#define S3 (SS * SS * SS)
#define VOLRADIUS 256.0f
#define CULL_EPS 1e-3f

// ---- DPP inclusive scans (gfx9 pattern: row_shr 1/2/4/8 + row_bcast 15/31) ----
template <int CTRL, int RM>
__device__ __forceinline__ float dpp_addf(float x) {
    int y = __builtin_amdgcn_update_dpp(0, __float_as_int(x), CTRL, RM, 0xF, false);
    return x + __int_as_float(y);
}
__device__ __forceinline__ float wave_incl_scan(float x) {
    x = dpp_addf<0x111, 0xF>(x);
    x = dpp_addf<0x112, 0xF>(x);
    x = dpp_addf<0x114, 0xF>(x);
    x = dpp_addf<0x118, 0xF>(x);
    x = dpp_addf<0x142, 0xA>(x);   // row_bcast:15 -> rows 1,3
    x = dpp_addf<0x143, 0xC>(x);   // row_bcast:31 -> rows 2,3
    return x;
}
__device__ __forceinline__ int wave_incl_scan_addi(int x) {
    int y;
    y = __builtin_amdgcn_update_dpp(0, x, 0x111, 0xF, 0xF, false); x += y;
    y = __builtin_amdgcn_update_dpp(0, x, 0x112, 0xF, 0xF, false); x += y;
    y = __builtin_amdgcn_update_dpp(0, x, 0x114, 0xF, 0xF, false); x += y;
    y = __builtin_amdgcn_update_dpp(0, x, 0x118, 0xF, 0xF, false); x += y;
    y = __builtin_amdgcn_update_dpp(0, x, 0x142, 0xA, 0xF, false); x += y;
    y = __builtin_amdgcn_update_dpp(0, x, 0x143, 0xC, 0xF, false); x += y;
    return x;
}

#define LERP4(a, b, f) make_float4(a.x*(1.f-(f)) + b.x*(f), a.y*(1.f-(f)) + b.y*(f), \
                                   a.z*(1.f-(f)) + b.z*(f), a.w*(1.f-(f)) + b.w*(f))

// template [K,4,S,S,S] -> ws [K,S,S,S,4] so each trilinear corner is one float4
__global__ __launch_bounds__(256) void transpose_tpl(const float* __restrict__ tpl,
                                                     float4* __restrict__ tw) {
    int i = blockIdx.x * blockDim.x + threadIdx.x;      // 0 .. K*S3
    if (i >= KK * S3) return;
    int k = i >> 12, v = i & (S3 - 1);
    const float* src = tpl + ((size_t)k * 4 * S3) + v;
    tw[i] = make_float4(src[0], src[S3], src[2 * S3], src[3 * S3]);
}

template <bool TR>
__global__ __launch_bounds__(256, 4) void raymarch_kernel(
    const float* __restrict__ viewpos,   // [3]
    const float* __restrict__ raydir,    // [H,W,3]
    const float* __restrict__ tpl,       // [K,4,S,S,S]
    const float* __restrict__ primpos,   // [K,3]
    const float* __restrict__ primrot,   // [K,3,3]
    const float* __restrict__ primscale, // [K,3]
    const float* __restrict__ dtp,       // [1]
    const float4* __restrict__ tw,       // [K,S3] rgba (if TR)
    float* __restrict__ out)
{
    const int lane = (int)(threadIdx.x & 63);
    const int wvid = (int)(threadIdx.x >> 6);      // wave within block (0..3)
    const int wid = __builtin_amdgcn_readfirstlane(
        (int)((blockIdx.x * blockDim.x + threadIdx.x) >> 6));
    if (wid >= HH * WW) return;
    // bijective swizzle: spread heavy central rows across the dispatch order
    const int pix = ((wid & 63) << 8) | (wid >> 6);

    __shared__ float4 accs[4][64];                 // per-(wave,step) RGBA partials
    accs[wvid][lane] = make_float4(0.f, 0.f, 0.f, 0.f);   // own-wave region

    const float vx = viewpos[0] / VOLRADIUS;
    const float vy = viewpos[1] / VOLRADIUS;
    const float vz = viewpos[2] / VOLRADIUS;
    const float dtn = dtp[0] / VOLRADIUS;

    const float Rx = raydir[pix*3+0], Ry = raydir[pix*3+1], Rz = raydir[pix*3+2];

    // slab vs [-1,1]^3, exactly as reference
    float t1x = (-1.f-vx)/Rx, t2x = (1.f-vx)/Rx;
    float t1y = (-1.f-vy)/Ry, t2y = (1.f-vy)/Ry;
    float t1z = (-1.f-vz)/Rz, t2z = (1.f-vz)/Rz;
    float tmin = fmaxf(fminf(t1x,t2x), fmaxf(fminf(t1y,t2y), fminf(t1z,t2z)));
    float tmax = fminf(fmaxf(t1x,t2x), fminf(fmaxf(t1y,t2y), fmaxf(t1z,t2z)));
    bool inter = tmin < tmax;
    float tmin_ = inter ? tmin : 0.f;
    float tmax_ = inter ? tmax : 0.f;
    float t0 = fmaxf(tmin_, 0.f);

    // this lane's primitive params, held live for cross-lane fetch later
    const float px = primpos[lane*3+0], py = primpos[lane*3+1], pz = primpos[lane*3+2];
    const float r00 = primrot[lane*9+0], r01 = primrot[lane*9+1], r02 = primrot[lane*9+2];
    const float r10 = primrot[lane*9+3], r11 = primrot[lane*9+4], r12 = primrot[lane*9+5];
    const float r20 = primrot[lane*9+6], r21 = primrot[lane*9+7], r22 = primrot[lane*9+8];
    const float sx = primscale[lane*3+0], sy = primscale[lane*3+1], sz = primscale[lane*3+2];

    // ---- cull: conservative ray-vs-OBB -> conservative STEP RANGE per prim ----
    int ilo = 0, icnt = 0;
    {
        float bb[3], dd[3];
        bb[0] = ((vx-px)*r00 + (vy-py)*r10 + (vz-pz)*r20) * sx;
        bb[1] = ((vx-px)*r01 + (vy-py)*r11 + (vz-pz)*r21) * sy;
        bb[2] = ((vx-px)*r02 + (vy-py)*r12 + (vz-pz)*r22) * sz;
        dd[0] = (Rx*r00 + Ry*r10 + Rz*r20) * sx;
        dd[1] = (Rx*r01 + Ry*r11 + Rz*r21) * sy;
        dd[2] = (Rx*r02 + Ry*r12 + Rz*r22) * sz;
        float tend = fminf(tmax_, t0 + 63.f*dtn);
        float te = t0, tx = tend;
#pragma unroll
        for (int j = 0; j < 3; ++j) {
            float ta, tb2;
            if (fabsf(dd[j]) > 1e-12f) {
                float inv = 1.f / dd[j];
                ta  = (-1.f - CULL_EPS - bb[j]) * inv;
                tb2 = ( 1.f + CULL_EPS - bb[j]) * inv;
            } else {
                bool ok = fabsf(bb[j]) <= 1.f + CULL_EPS;
                ta  = ok ? -3e38f :  3e38f;
                tb2 = ok ?  3e38f : -3e38f;
            }
            te = fmaxf(te, fminf(ta, tb2));
            tx = fminf(tx, fmaxf(ta, tb2));
        }
        if (te <= tx) {
            // tightened conservative bounds: true-inside steps sit >= ~5e-3 step
            // units inside [te,tx] (CULL_EPS margin / |d| >= 1.25e-4 t-units);
            // 0.01 margin keeps a strict superset while dropping ~2 cand/prim.
            float flo = (te - t0) / dtn - 0.01f;
            float fhi = (tx - t0) / dtn + 0.01f;
            ilo = max(0, (int)ceilf(flo));
            int ihi = min(63, (int)floorf(fhi));
            icnt = max(0, ihi - ilo + 1);
        }
    }

    float sv0, sv1, sv2, sv3;

    if (TR) {
        // ---- closed-form candidate enumeration, pure-register owner search ----
        const int Ainc  = wave_incl_scan_addi(icnt);
        const int start = Ainc - icnt;                 // exclusive prefix (sorted by lane)
        const int Ctot  = __builtin_amdgcn_readlane(Ainc, 63);
        const int nw    = (Ctot + 63) >> 6;

        for (int b = 0; b < nw; ++b) {
            const int s  = (b << 6) + lane;            // candidate slot
            const bool act = s < Ctot;

            // owner = largest lane p with start[p] <= s  (start[0]==0 <= s)
            int p = 0;
#pragma unroll
            for (int st = 32; st > 0; st >>= 1) {
                int cand = p | st;                     // <= 63 by construction
                int sp = __shfl(start, cand, 64);
                if (sp <= s) p = cand;
            }
            const int pst = __shfl(start, p, 64);
            const int il  = __shfl(ilo,   p, 64);
            const int ic  = __shfl(icnt,  p, 64);
            const int i   = il + (s - pst);            // step index, <= ihi <= 63 when in range
            const bool inrange = act && (s - pst) < ic;

            // fetch prim p's params cross-lane (bit-exact register moves)
            float qpx = __shfl(px, p, 64), qpy = __shfl(py, p, 64), qpz = __shfl(pz, p, 64);
            float q00 = __shfl(r00, p, 64), q01 = __shfl(r01, p, 64), q02 = __shfl(r02, p, 64);
            float q10 = __shfl(r10, p, 64), q11 = __shfl(r11, p, 64), q12 = __shfl(r12, p, 64);
            float q20 = __shfl(r20, p, 64), q21 = __shfl(r21, p, 64), q22 = __shfl(r22, p, 64);
            float qsx = __shfl(sx, p, 64), qsy = __shfl(sy, p, 64), qsz = __shfl(sz, p, 64);

            // exact per-candidate math (identical expressions to reference)
            float ti = t0 + (float)i * dtn;
            float posx = vx + Rx*ti, posy = vy + Ry*ti, posz = vz + Rz*ti;
            float xmx = posx-qpx, xmy = posy-qpy, xmz = posz-qpz;
            float y0 = (xmx*q00 + xmy*q10 + xmz*q20) * qsx;
            float y1 = (xmx*q01 + xmy*q11 + xmz*q21) * qsy;
            float y2 = (xmx*q02 + xmy*q12 + xmz*q22) * qsz;
            bool samp = inrange && (ti < tmax_) &&
                        fabsf(y0) < 1.f && fabsf(y1) < 1.f && fabsf(y2) < 1.f;
            if (samp) {
                float gx = (y0+1.f)*(0.5f*(SS-1));
                float gy = (y1+1.f)*(0.5f*(SS-1));
                float gz = (y2+1.f)*(0.5f*(SS-1));
                int x0  = min(max((int)floorf(gx), 0), SS-2);
                int y0i = min(max((int)floorf(gy), 0), SS-2);
                int z0  = min(max((int)floorf(gz), 0), SS-2);
                float fx = gx-(float)x0, fy = gy-(float)y0i, fz = gz-(float)z0;
                int idx = z0*(SS*SS) + y0i*SS + x0;
                const float4* tb = tw + ((size_t)p << 12) + idx;
                float4 c000 = tb[0],          c001 = tb[1];
                float4 c010 = tb[SS],         c011 = tb[SS+1];
                float4 c100 = tb[SS*SS],      c101 = tb[SS*SS+1];
                float4 c110 = tb[SS*SS+SS],   c111 = tb[SS*SS+SS+1];
                float4 c00 = LERP4(c000, c001, fx);
                float4 c01 = LERP4(c010, c011, fx);
                float4 c10 = LERP4(c100, c101, fx);
                float4 c11 = LERP4(c110, c111, fx);
                float4 e0  = LERP4(c00, c01, fy);
                float4 e1  = LERP4(c10, c11, fy);
                float* ap = (float*)&accs[wvid][i];
                atomicAdd(ap + 0, e0.x*(1.f-fz) + e1.x*fz);
                atomicAdd(ap + 1, e0.y*(1.f-fz) + e1.y*fz);
                atomicAdd(ap + 2, e0.z*(1.f-fz) + e1.z*fz);
                atomicAdd(ap + 3, e0.w*(1.f-fz) + e1.w*fz);
            }
        }
        // own-wave DS ops complete in order; no cross-wave sharing -> no barrier
        float4 a = accs[wvid][lane];
        sv0 = a.x; sv1 = a.y; sv2 = a.z; sv3 = a.w;
    } else {
        // fallback: r6-style uniform prim loop on original layout
        unsigned long long mask = __ballot(icnt > 0);
        const float t = t0 + (float)lane * dtn;
        const bool tvalid = t < tmax_;
        const float posx = vx + Rx*t, posy = vy + Ry*t, posz = vz + Rz*t;
        sv0 = sv1 = sv2 = sv3 = 0.f;
        while (mask) {
            const int ku = __builtin_amdgcn_readfirstlane(__ffsll(mask) - 1);
            mask &= mask - 1;
            const float qpx = primpos[ku*3+0], qpy = primpos[ku*3+1], qpz = primpos[ku*3+2];
            const float q00 = primrot[ku*9+0], q01 = primrot[ku*9+1], q02 = primrot[ku*9+2];
            const float q10 = primrot[ku*9+3], q11 = primrot[ku*9+4], q12 = primrot[ku*9+5];
            const float q20 = primrot[ku*9+6], q21 = primrot[ku*9+7], q22 = primrot[ku*9+8];
            const float qsx = primscale[ku*3+0], qsy = primscale[ku*3+1], qsz = primscale[ku*3+2];
            float xmx = posx-qpx, xmy = posy-qpy, xmz = posz-qpz;
            float y0 = (xmx*q00 + xmy*q10 + xmz*q20) * qsx;
            float y1 = (xmx*q01 + xmy*q11 + xmz*q21) * qsy;
            float y2 = (xmx*q02 + xmy*q12 + xmz*q22) * qsz;
            bool samp = tvalid && fabsf(y0) < 1.f && fabsf(y1) < 1.f && fabsf(y2) < 1.f;
            if (samp) {
                float gx = (y0+1.f)*(0.5f*(SS-1));
                float gy = (y1+1.f)*(0.5f*(SS-1));
                float gz = (y2+1.f)*(0.5f*(SS-1));
                int x0  = min(max((int)floorf(gx), 0), SS-2);
                int y0i = min(max((int)floorf(gy), 0), SS-2);
                int z0  = min(max((int)floorf(gz), 0), SS-2);
                float fx = gx-(float)x0, fy = gy-(float)y0i, fz = gz-(float)z0;
                int idx = z0*(SS*SS) + y0i*SS + x0;
                const float* tp = tpl + (size_t)ku * (4 * S3);
                float sv[4];
#pragma unroll
                for (int c = 0; c < 4; ++c) {
                    const float* tc = tp + c * S3;
                    float c000 = tc[idx],              c001 = tc[idx+1];
                    float c010 = tc[idx+SS],           c011 = tc[idx+SS+1];
                    float c100 = tc[idx+SS*SS],        c101 = tc[idx+SS*SS+1];
                    float c110 = tc[idx+SS*SS+SS],     c111 = tc[idx+SS*SS+SS+1];
                    float c00 = c000*(1.f-fx) + c001*fx;
                    float c01 = c010*(1.f-fx) + c011*fx;
                    float c10 = c100*(1.f-fx) + c101*fx;
                    float c11 = c110*(1.f-fx) + c111*fx;
                    sv[c] = (c00*(1.f-fy) + c01*fy)*(1.f-fz)
                          + (c10*(1.f-fy) + c11*fy)*fz;
                }
                sv0 += sv[0]; sv1 += sv[1]; sv2 += sv[2]; sv3 += sv[3];
            }
        }
    }

    // ---- compositing in closed form: alpha >= 0 => accA = min(prefix,1) ----
    const float tl = t0 + (float)lane * dtn;
    const bool tvalid = tl < tmax_;
    float alpha = tvalid ? sv3 * dtn : 0.f;
    float A = wave_incl_scan(alpha);               // inclusive prefix of alpha
    float Aex = __shfl_up(A, 1, 64);
    if (lane == 0) Aex = 0.f;
    float contrib = fminf(Aex + alpha, 1.f) - fminf(Aex, 1.f);
    float cr = wave_incl_scan(sv0 * contrib);      // lane63 = total
    float cg = wave_incl_scan(sv1 * contrib);
    float cb = wave_incl_scan(sv2 * contrib);
    float At = fminf(A, 1.f);

    if (lane == 63) {
        out[0*HH*WW + pix] = cr;
        out[1*HH*WW + pix] = cg;
        out[2*HH*WW + pix] = cb;
        out[3*HH*WW + pix] = At;
        const int b1 = 4*HH*WW;
        out[b1 + pix*3+0] = vx + Rx*tmin_;
        out[b1 + pix*3+1] = vy + Ry*tmin_;
        out[b1 + pix*3+2] = vz + Rz*tmin_;
        const int b2 = b1 + HH*WW*3;
        out[b2 + pix*3+0] = vx + Rx*tmax_;
        out[b2 + pix*3+1] = vy + Ry*tmax_;
        out[b2 + pix*3+2] = vz + Rz*tmax_;
    }
}

extern "C" void kernel_launch(void* const* d_in, const int* in_sizes, int n_in,
                              void* d_out, int out_size, void* d_ws, size_t ws_size,
                              hipStream_t stream) {
    const float* viewpos   = (const float*)d_in[0];
    // d_in[1] = viewrot, unused by the reference
    const float* raydir    = (const float*)d_in[2];
    const float* tpl       = (const float*)d_in[3];
    const float* primpos   = (const float*)d_in[4];
    const float* primrot   = (const float*)d_in[5];
    const float* primscale = (const float*)d_in[6];
    const float* dtp       = (const float*)d_in[7];
    float* out = (float*)d_out;

    const size_t twbytes = (size_t)KK * S3 * 4 * sizeof(float);  // 4 MiB
    dim3 block(256), grid(HH * WW * 64 / 256);                    // 4096 blocks

    if (ws_size >= twbytes) {
        transpose_tpl<<<dim3((KK * S3 + 255) / 256), block, 0, stream>>>(tpl, (float4*)d_ws);
        raymarch_kernel<true><<<grid, block, 0, stream>>>(
            viewpos, raydir, tpl, primpos, primrot, primscale, dtp,
            (const float4*)d_ws, out);
    } else {
        raymarch_kernel<false><<<grid, block, 0, stream>>>(
            viewpos, raydir, tpl, primpos, primrot, primscale, dtp,
            (const float4*)d_ws, out);
    }
}